// Round 13
// baseline (50.279 us; speedup 1.0000x reference)
//
#include <hip/hip_runtime.h>
#include <math.h>

#define N 16384
#define K 32
#define D 16
#define S 2048
#define E 500000
#define EPSF 1e-6f
#define B 256

// ---- workspace layout (float offsets) ----
#define OFF_Z      0                       // K*N (col-major softmax result)
#define OFF_CSPART (K*N)                   // 64*32 colsum partials
#define OFF_MPART  (OFF_CSPART + 2048)     // 64*1024 M partials
#define OFF_AZC    (OFF_MPART + 65536)     // 512 (D x K)
#define OFF_X      (OFF_AZC + 512)         // N*D row-major (64B-aligned rows)
#define OFF_XST    (OFF_X + N*D)           // D*S transposed samples (pairwise)
#define OFF_BS     (OFF_XST + D*S)         // S sampled betas

#define GPAIR 256
#define GEDGE 1024
#define GPE   (GPAIR + GEDGE)

__device__ __forceinline__ float block_reduce_sum(float v, float* sdata) {
    int tid = threadIdx.x;
    sdata[tid] = v;
    __syncthreads();
    for (int s = B >> 1; s > 0; s >>= 1) {
        if (tid < s) sdata[tid] += sdata[tid + s];
        __syncthreads();
    }
    return sdata[0];
}

// K1: blocks 0..63 softmax cols + ZTG colsum partials; 64..127 Mpart partials.
__global__ __launch_bounds__(B) void k_ab(
    const float* __restrict__ Zp, const float* __restrict__ Gate,
    const int* __restrict__ sample_idx, float* __restrict__ ws)
{
    __shared__ __align__(16) float sf[256 * 33 + 256];
    int tid = threadIdx.x, bid = blockIdx.x;
    if (bid < 64) {
        int n = bid * B + tid;
        float z[K];
        float m = -1e30f;
#pragma unroll
        for (int k = 0; k < K; ++k) { z[k] = Zp[k * N + n]; m = fmaxf(m, z[k]); }
        float s = 0.f;
#pragma unroll
        for (int k = 0; k < K; ++k) { z[k] = expf(z[k] - m); s += z[k]; }
        float inv = 1.f / s;
#pragma unroll
        for (int k = 0; k < K; ++k) { z[k] *= inv; ws[OFF_Z + k * N + n] = z[k]; }
        float t[K];
        const float4* gp = reinterpret_cast<const float4*>(Gate + (size_t)n * K);
#pragma unroll
        for (int q = 0; q < K / 4; ++q) {
            float4 g = gp[q];
            t[4*q+0] = z[4*q+0] / (1.f + expf(-g.x));
            t[4*q+1] = z[4*q+1] / (1.f + expf(-g.y));
            t[4*q+2] = z[4*q+2] / (1.f + expf(-g.z));
            t[4*q+3] = z[4*q+3] / (1.f + expf(-g.w));
        }
#pragma unroll
        for (int k = 0; k < K; ++k) sf[tid * 33 + k] = t[k];
        __syncthreads();
        int kk = tid & 31, rg = tid >> 5;
        float acc = 0.f;
#pragma unroll
        for (int r = 0; r < 32; ++r) acc += sf[(rg * 32 + r) * 33 + kk];
        sf[256 * 33 + rg * 32 + kk] = acc;
        __syncthreads();
        if (rg == 0) {
            float tot = 0.f;
#pragma unroll
            for (int g2 = 0; g2 < 8; ++g2) tot += sf[256 * 33 + g2 * 32 + kk];
            ws[OFF_CSPART + bid * 32 + kk] = tot;
        }
    } else {
        // 32 samples per block, 8 threads per sample
        float* sZ = sf;           // 32*32
        float* sT = sf + 1024;    // 32*32
        int slot = tid >> 3, sub = tid & 7;
        int idx = sample_idx[(bid - 64) * 32 + slot];
        float za[4];
        float m = -1e30f;
#pragma unroll
        for (int q = 0; q < 4; ++q) {
            za[q] = Zp[(sub + 8 * q) * N + idx];
            m = fmaxf(m, za[q]);
        }
#pragma unroll
        for (int off = 1; off < 8; off <<= 1) m = fmaxf(m, __shfl_xor(m, off, 8));
        float ssum = 0.f;
#pragma unroll
        for (int q = 0; q < 4; ++q) { za[q] = expf(za[q] - m); ssum += za[q]; }
#pragma unroll
        for (int off = 1; off < 8; off <<= 1) ssum += __shfl_xor(ssum, off, 8);
        float inv = 1.f / ssum;
#pragma unroll
        for (int q = 0; q < 4; ++q) {
            int a = sub + 8 * q;
            float zv = za[q] * inv;
            float g = Gate[(size_t)idx * K + a];
            sZ[slot * 32 + a] = zv;
            sT[slot * 32 + a] = zv / (1.f + expf(-g));
        }
        __syncthreads();
#pragma unroll
        for (int e4 = 0; e4 < 4; ++e4) {
            int ent = tid + e4 * B;
            int a = ent >> 5, b = ent & 31;
            float acc = 0.f;
#pragma unroll
            for (int sl = 0; sl < 32; ++sl) acc += sZ[sl * 32 + a] * sT[sl * 32 + b];
            ws[OFF_MPART + (size_t)(bid - 64) * 1024 + ent] = acc;
        }
    }
}

// K2 (grid 32): block b: M[:,b] = sum_p Mpart[p,:,b]/cs[b]; AZC[:,b] = A @ M[:,b]
__global__ __launch_bounds__(B) void k_m(
    const float* __restrict__ A, float* __restrict__ ws)
{
    __shared__ float sMp[256];
    __shared__ float sM[32];
    __shared__ float scs;
    int tid = threadIdx.x, b = blockIdx.x;
    int pg = tid >> 5, a = tid & 31;
    float acc = 0.f;
#pragma unroll
    for (int pp = 0; pp < 8; ++pp)
        acc += ws[OFF_MPART + (size_t)(pp * 8 + pg) * 1024 + a * 32 + b];
    sMp[tid] = acc;
    if (tid < 64) {
        float v = ws[OFF_CSPART + tid * 32 + b];
#pragma unroll
        for (int off = 32; off > 0; off >>= 1) v += __shfl_down(v, off, 64);
        if (tid == 0) scs = v;
    }
    __syncthreads();
    if (tid < 32) {
        float m = 0.f;
#pragma unroll
        for (int g = 0; g < 8; ++g) m += sMp[g * 32 + tid];
        sM[tid] = m / scs;
    }
    __syncthreads();
    if (tid < 16) {
        float azc = 0.f;
#pragma unroll
        for (int aa = 0; aa < K; ++aa) azc += A[tid * K + aa] * sM[aa];
        ws[OFF_AZC + tid * 32 + b] = azc;
    }
}

// K3 (grid 320): blocks 0..255 -> X rows (64 each, row-major);
//                256..319 -> XST (transposed samples) + bs (32 samples each).
// Also zeroes out[0] (stream-ordered before k_pe's atomics).
__global__ __launch_bounds__(B) void k_x(
    const float* __restrict__ beta, const int* __restrict__ sample_idx,
    float* __restrict__ ws, float* __restrict__ out)
{
    __shared__ float sA[512];
    int tid = threadIdx.x, bid = blockIdx.x;
    if (bid == 0 && tid == 0) out[0] = 0.f;
    sA[tid] = ws[OFF_AZC + tid];
    sA[tid + B] = ws[OFF_AZC + tid + B];
    __syncthreads();
    if (bid < 256) {
        int n = bid * 64 + (tid >> 2);
        int dq = tid & 3;
        float x0 = 0.f, x1 = 0.f, x2 = 0.f, x3 = 0.f;
#pragma unroll
        for (int k = 0; k < K; ++k) {
            float zk = ws[OFF_Z + k * N + n];
            x0 = fmaf(sA[(dq * 4 + 0) * 32 + k], zk, x0);
            x1 = fmaf(sA[(dq * 4 + 1) * 32 + k], zk, x1);
            x2 = fmaf(sA[(dq * 4 + 2) * 32 + k], zk, x2);
            x3 = fmaf(sA[(dq * 4 + 3) * 32 + k], zk, x3);
        }
        float4 o; o.x = x0; o.y = x1; o.z = x2; o.w = x3;
        *reinterpret_cast<float4*>(ws + OFF_X + (size_t)n * D + dq * 4) = o;
    } else {
        // 32 samples/block, 8 threads/sample, each thread 2 dims; write TRANSPOSED
        int slot = tid >> 3, sub = tid & 7;
        int sslot = (bid - 256) * 32 + slot;
        int idx = sample_idx[sslot];
        float x0 = 0.f, x1 = 0.f;
#pragma unroll
        for (int k = 0; k < K; ++k) {
            float zk = ws[OFF_Z + (size_t)k * N + idx];
            x0 = fmaf(sA[(2 * sub + 0) * 32 + k], zk, x0);
            x1 = fmaf(sA[(2 * sub + 1) * 32 + k], zk, x1);
        }
        ws[OFF_XST + (size_t)(2 * sub + 0) * S + sslot] = x0;
        ws[OFF_XST + (size_t)(2 * sub + 1) * S + sslot] = x1;
        if (sub == 0) ws[OFF_BS + sslot] = beta[idx];
    }
}

// K4 (grid 1280): blocks 0..255 pairwise (8 rows each, coalesced XST reads);
//                 blocks 256..1279 edges (4 lanes/edge, coalesced row quads).
// Each block atomically adds its signed contribution to out[0]:
// edge blocks +totE, pair blocks -0.5*e^2*totP. No fences (r8 lesson: agent
// fences cost ~40us at this block count; bare atomics are cheap).
__global__ __launch_bounds__(B) void k_pe(
    const float* __restrict__ beta, const int* __restrict__ sparse_i,
    const int* __restrict__ sparse_j, float* __restrict__ ws,
    float* __restrict__ out)
{
    __shared__ float sdata[256];
    __shared__ float sXr[8 * D];
    __shared__ float sbr[8];
    int tid = threadIdx.x, bid = blockIdx.x;

    if (bid < GPAIR) {
        int r0 = bid * 8;
        if (tid < 8 * D) {
            int r = tid >> 4, d = tid & 15;
            sXr[r * D + d] = ws[OFF_XST + (size_t)d * S + r0 + r];
            if (d == 0) sbr[r] = ws[OFF_BS + r0 + r];
        }
        __syncthreads();
        float accP = 0.f;
        for (int t = tid; t < S; t += B) {
            float xt[D];
#pragma unroll
            for (int d = 0; d < D; ++d) xt[d] = ws[OFF_XST + (size_t)d * S + t];  // coalesced
            float bt = ws[OFF_BS + t];
#pragma unroll
            for (int r = 0; r < 8; ++r) {
                float d2 = 0.f;
#pragma unroll
                for (int d = 0; d < D; ++d) {
                    float df = sXr[r * D + d] - xt[d] + EPSF;
                    d2 = fmaf(df, df, d2);
                }
                float v = expf(sbr[r] + bt - sqrtf(d2));
                accP += (r0 + r == t) ? 0.f : v;
            }
        }
        __syncthreads();
        float totP = block_reduce_sum(accP, sdata);
        if (tid == 0) {
            float e = expf(1.0f);
            atomicAdd(out, -0.5f * e * e * totP);
        }
    } else {
        int quad = tid >> 2, q = tid & 3;
        float accE = 0.f;
        for (int e = (bid - GPAIR) * 64 + quad; e < E; e += GEDGE * 64) {
            int i = sparse_i[e], j = sparse_j[e];
            float4 a4 = *reinterpret_cast<const float4*>(ws + OFF_X + (size_t)i * D + q * 4);
            float4 b4 = *reinterpret_cast<const float4*>(ws + OFF_X + (size_t)j * D + q * 4);
            float df, d2 = 0.f;
            df = a4.x - b4.x + EPSF; d2 = fmaf(df, df, d2);
            df = a4.y - b4.y + EPSF; d2 = fmaf(df, df, d2);
            df = a4.z - b4.z + EPSF; d2 = fmaf(df, df, d2);
            df = a4.w - b4.w + EPSF; d2 = fmaf(df, df, d2);
            d2 += __shfl_xor(d2, 1, 4);
            d2 += __shfl_xor(d2, 2, 4);
            if (q == 0) accE += beta[i] + beta[j] - sqrtf(d2);
        }
        __syncthreads();
        float totE = block_reduce_sum(accE, sdata);
        if (tid == 0) atomicAdd(out, totE);
    }
}

extern "C" void kernel_launch(void* const* d_in, const int* in_sizes, int n_in,
                              void* d_out, int out_size, void* d_ws, size_t ws_size,
                              hipStream_t stream) {
    const float* beta = (const float*)d_in[0];
    const float* A    = (const float*)d_in[1];
    const float* Zp   = (const float*)d_in[2];
    const float* Gate = (const float*)d_in[3];
    const int* sample_idx = (const int*)d_in[4];
    const int* sparse_i   = (const int*)d_in[5];
    const int* sparse_j   = (const int*)d_in[6];
    float* ws  = (float*)d_ws;
    float* out = (float*)d_out;

    k_ab<<<128, B, 0, stream>>>(Zp, Gate, sample_idx, ws);
    k_m <<<32,  B, 0, stream>>>(A, ws);
    k_x <<<320, B, 0, stream>>>(beta, sample_idx, ws, out);
    k_pe<<<GPE, B, 0, stream>>>(beta, sparse_i, sparse_j, ws, out);
}

// Round 14
// 45.510 us; speedup vs baseline: 1.1048x; 1.1048x over previous
//
#include <hip/hip_runtime.h>
#include <math.h>

#define N 16384
#define K 32
#define D 16
#define S 2048
#define E 500000
#define EPSF 1e-6f
#define B 256

// ---- workspace layout (float offsets) ----
#define OFF_Z      0                       // K*N (col-major softmax result)
#define OFF_CSPART (K*N)                   // 64*32 colsum partials
#define OFF_AZCP   (OFF_CSPART + 2048)     // 64*512 partial AZC planes
#define OFF_X      (OFF_AZCP + 32768)      // N*D row-major (64B-aligned rows)
#define OFF_XST    (OFF_X + N*D)           // D*S transposed samples (pairwise)
#define OFF_BS     (OFF_XST + D*S)         // S sampled betas
#define OFF_PD1    (OFF_BS + S)            // 256 pairwise partials
#define OFF_PD2    (OFF_PD1 + 256)         // 1024 edge partials

#define GPAIR 256
#define GEDGE 1024
#define GPE   (GPAIR + GEDGE)

__device__ __forceinline__ float block_reduce_sum(float v, float* sdata) {
    int tid = threadIdx.x;
    sdata[tid] = v;
    __syncthreads();
    for (int s = B >> 1; s > 0; s >>= 1) {
        if (tid < s) sdata[tid] += sdata[tid + s];
        __syncthreads();
    }
    return sdata[0];
}

// K1: blocks 0..63 softmax cols + ZTG colsum partials;
//     blocks 64..127: Mpart partials + per-block A@Mp -> AZCpart plane.
__global__ __launch_bounds__(B) void k_ab(
    const float* __restrict__ Zp, const float* __restrict__ Gate,
    const int* __restrict__ sample_idx, const float* __restrict__ A,
    float* __restrict__ ws)
{
    __shared__ __align__(16) float sf[256 * 33 + 256];
    int tid = threadIdx.x, bid = blockIdx.x;
    if (bid < 64) {
        int n = bid * B + tid;
        float z[K];
        float m = -1e30f;
#pragma unroll
        for (int k = 0; k < K; ++k) { z[k] = Zp[k * N + n]; m = fmaxf(m, z[k]); }
        float s = 0.f;
#pragma unroll
        for (int k = 0; k < K; ++k) { z[k] = expf(z[k] - m); s += z[k]; }
        float inv = 1.f / s;
#pragma unroll
        for (int k = 0; k < K; ++k) { z[k] *= inv; ws[OFF_Z + k * N + n] = z[k]; }
        float t[K];
        const float4* gp = reinterpret_cast<const float4*>(Gate + (size_t)n * K);
#pragma unroll
        for (int q = 0; q < K / 4; ++q) {
            float4 g = gp[q];
            t[4*q+0] = z[4*q+0] / (1.f + expf(-g.x));
            t[4*q+1] = z[4*q+1] / (1.f + expf(-g.y));
            t[4*q+2] = z[4*q+2] / (1.f + expf(-g.z));
            t[4*q+3] = z[4*q+3] / (1.f + expf(-g.w));
        }
#pragma unroll
        for (int k = 0; k < K; ++k) sf[tid * 33 + k] = t[k];
        __syncthreads();
        int kk = tid & 31, rg = tid >> 5;
        float acc = 0.f;
#pragma unroll
        for (int r = 0; r < 32; ++r) acc += sf[(rg * 32 + r) * 33 + kk];
        sf[256 * 33 + rg * 32 + kk] = acc;
        __syncthreads();
        if (rg == 0) {
            float tot = 0.f;
#pragma unroll
            for (int g2 = 0; g2 < 8; ++g2) tot += sf[256 * 33 + g2 * 32 + kk];
            ws[OFF_CSPART + bid * 32 + kk] = tot;
        }
    } else {
        // 32 samples per block, 8 threads per sample -> Mp in LDS -> A@Mp plane
        float* sZ = sf;           // 32*32
        float* sT = sf + 1024;    // 32*32
        float* sM = sf + 2048;    // 32*32 (Mp)
        int slot = tid >> 3, sub = tid & 7;
        int idx = sample_idx[(bid - 64) * 32 + slot];
        float za[4];
        float m = -1e30f;
#pragma unroll
        for (int q = 0; q < 4; ++q) {
            za[q] = Zp[(sub + 8 * q) * N + idx];
            m = fmaxf(m, za[q]);
        }
#pragma unroll
        for (int off = 1; off < 8; off <<= 1) m = fmaxf(m, __shfl_xor(m, off, 8));
        float ssum = 0.f;
#pragma unroll
        for (int q = 0; q < 4; ++q) { za[q] = expf(za[q] - m); ssum += za[q]; }
#pragma unroll
        for (int off = 1; off < 8; off <<= 1) ssum += __shfl_xor(ssum, off, 8);
        float inv = 1.f / ssum;
#pragma unroll
        for (int q = 0; q < 4; ++q) {
            int a = sub + 8 * q;
            float zv = za[q] * inv;
            float g = Gate[(size_t)idx * K + a];
            sZ[slot * 32 + a] = zv;
            sT[slot * 32 + a] = zv / (1.f + expf(-g));
        }
        __syncthreads();
#pragma unroll
        for (int e4 = 0; e4 < 4; ++e4) {
            int ent = tid + e4 * B;
            int a = ent >> 5, b = ent & 31;
            float acc = 0.f;
#pragma unroll
            for (int sl = 0; sl < 32; ++sl) acc += sZ[sl * 32 + a] * sT[sl * 32 + b];
            sM[ent & 1023] = acc;   // ent in [0,1024)
        }
        __syncthreads();
        // AZCpart[d][b] = sum_a A[d][a] * Mp[a][b]  (512 entries, 2/thread)
#pragma unroll
        for (int e2 = 0; e2 < 2; ++e2) {
            int ent = tid + e2 * B;
            int d = ent >> 5, b = ent & 31;
            float azc = 0.f;
#pragma unroll
            for (int a = 0; a < K; ++a) azc += A[d * K + a] * sM[a * 32 + b];
            ws[OFF_AZCP + (size_t)(bid - 64) * 512 + ent] = azc;
        }
    }
}

// K2 (grid 320): prologue: reduce 64 AZCpart planes + colsum -> AZC in LDS.
// Then blocks 0..255 -> X rows (64 each, row-major);
//      256..319 -> XST (transposed samples) + bs (32 samples each).
__global__ __launch_bounds__(B) void k_x(
    const float* __restrict__ beta, const int* __restrict__ sample_idx,
    float* __restrict__ ws)
{
    __shared__ float sA[512];
    __shared__ float scs[32];
    int tid = threadIdx.x, bid = blockIdx.x;
    // colsum totals
    if (tid < 32) {
        float cs = 0.f;
#pragma unroll
        for (int p = 0; p < 64; ++p) cs += ws[OFF_CSPART + p * 32 + tid];
        scs[tid] = cs;
    }
    // reduce AZC planes (coalesced: consecutive threads -> consecutive entries)
    float a0 = 0.f, a1 = 0.f;
#pragma unroll
    for (int p = 0; p < 64; ++p) {
        a0 += ws[OFF_AZCP + (size_t)p * 512 + tid];
        a1 += ws[OFF_AZCP + (size_t)p * 512 + tid + B];
    }
    __syncthreads();
    sA[tid]     = a0 / scs[tid & 31];
    sA[tid + B] = a1 / scs[tid & 31];
    __syncthreads();
    if (bid < 256) {
        int n = bid * 64 + (tid >> 2);
        int dq = tid & 3;
        float x0 = 0.f, x1 = 0.f, x2 = 0.f, x3 = 0.f;
#pragma unroll
        for (int k = 0; k < K; ++k) {
            float zk = ws[OFF_Z + k * N + n];
            x0 = fmaf(sA[(dq * 4 + 0) * 32 + k], zk, x0);
            x1 = fmaf(sA[(dq * 4 + 1) * 32 + k], zk, x1);
            x2 = fmaf(sA[(dq * 4 + 2) * 32 + k], zk, x2);
            x3 = fmaf(sA[(dq * 4 + 3) * 32 + k], zk, x3);
        }
        float4 o; o.x = x0; o.y = x1; o.z = x2; o.w = x3;
        *reinterpret_cast<float4*>(ws + OFF_X + (size_t)n * D + dq * 4) = o;
    } else {
        // 32 samples/block, 8 threads/sample, each thread 2 dims; write TRANSPOSED
        int slot = tid >> 3, sub = tid & 7;
        int sslot = (bid - 256) * 32 + slot;
        int idx = sample_idx[sslot];
        float x0 = 0.f, x1 = 0.f;
#pragma unroll
        for (int k = 0; k < K; ++k) {
            float zk = ws[OFF_Z + (size_t)k * N + idx];
            x0 = fmaf(sA[(2 * sub + 0) * 32 + k], zk, x0);
            x1 = fmaf(sA[(2 * sub + 1) * 32 + k], zk, x1);
        }
        ws[OFF_XST + (size_t)(2 * sub + 0) * S + sslot] = x0;
        ws[OFF_XST + (size_t)(2 * sub + 1) * S + sslot] = x1;
        if (sub == 0) ws[OFF_BS + sslot] = beta[idx];
    }
}

// K3 (grid 1280): blocks 0..255 pairwise (8 rows each, coalesced XST reads);
//                 blocks 256..1279 edges (4 lanes/edge, coalesced row quads).
// No fences, no atomics (r8/r13 lessons).
__global__ __launch_bounds__(B) void k_pe(
    const float* __restrict__ beta, const int* __restrict__ sparse_i,
    const int* __restrict__ sparse_j, float* __restrict__ ws)
{
    __shared__ float sdata[256];
    __shared__ float sXr[8 * D];
    __shared__ float sbr[8];
    int tid = threadIdx.x, bid = blockIdx.x;

    if (bid < GPAIR) {
        int r0 = bid * 8;
        if (tid < 8 * D) {
            int r = tid >> 4, d = tid & 15;
            sXr[r * D + d] = ws[OFF_XST + (size_t)d * S + r0 + r];
            if (d == 0) sbr[r] = ws[OFF_BS + r0 + r];
        }
        __syncthreads();
        float accP = 0.f;
        for (int t = tid; t < S; t += B) {
            float xt[D];
#pragma unroll
            for (int d = 0; d < D; ++d) xt[d] = ws[OFF_XST + (size_t)d * S + t];  // coalesced
            float bt = ws[OFF_BS + t];
#pragma unroll
            for (int r = 0; r < 8; ++r) {
                float d2 = 0.f;
#pragma unroll
                for (int d = 0; d < D; ++d) {
                    float df = sXr[r * D + d] - xt[d] + EPSF;
                    d2 = fmaf(df, df, d2);
                }
                float v = expf(sbr[r] + bt - sqrtf(d2));
                accP += (r0 + r == t) ? 0.f : v;
            }
        }
        __syncthreads();
        float totP = block_reduce_sum(accP, sdata);
        if (tid == 0) ws[OFF_PD1 + bid] = totP;
    } else {
        int quad = tid >> 2, q = tid & 3;
        float accE = 0.f;
        for (int e = (bid - GPAIR) * 64 + quad; e < E; e += GEDGE * 64) {
            int i = sparse_i[e], j = sparse_j[e];
            float4 a4 = *reinterpret_cast<const float4*>(ws + OFF_X + (size_t)i * D + q * 4);
            float4 b4 = *reinterpret_cast<const float4*>(ws + OFF_X + (size_t)j * D + q * 4);
            float df, d2 = 0.f;
            df = a4.x - b4.x + EPSF; d2 = fmaf(df, df, d2);
            df = a4.y - b4.y + EPSF; d2 = fmaf(df, df, d2);
            df = a4.z - b4.z + EPSF; d2 = fmaf(df, df, d2);
            df = a4.w - b4.w + EPSF; d2 = fmaf(df, df, d2);
            d2 += __shfl_xor(d2, 1, 4);
            d2 += __shfl_xor(d2, 2, 4);
            if (q == 0) accE += beta[i] + beta[j] - sqrtf(d2);
        }
        __syncthreads();
        float totE = block_reduce_sum(accE, sdata);
        if (tid == 0) ws[OFF_PD2 + (bid - GPAIR)] = totE;
    }
}

// K4 (1 block): final reduction.
__global__ __launch_bounds__(B) void k_fin(float* __restrict__ ws,
                                           float* __restrict__ out)
{
    __shared__ float sdata[256];
    int tid = threadIdx.x;
    float s1 = block_reduce_sum(ws[OFF_PD1 + tid], sdata);
    __syncthreads();
    float v2 = ws[OFF_PD2 + tid] + ws[OFF_PD2 + tid + 256]
             + ws[OFF_PD2 + tid + 512] + ws[OFF_PD2 + tid + 768];
    float s2 = block_reduce_sum(v2, sdata);
    if (tid == 0) {
        float e = expf(1.0f);
        out[0] = s2 - 0.5f * e * e * s1;
    }
}

extern "C" void kernel_launch(void* const* d_in, const int* in_sizes, int n_in,
                              void* d_out, int out_size, void* d_ws, size_t ws_size,
                              hipStream_t stream) {
    const float* beta = (const float*)d_in[0];
    const float* A    = (const float*)d_in[1];
    const float* Zp   = (const float*)d_in[2];
    const float* Gate = (const float*)d_in[3];
    const int* sample_idx = (const int*)d_in[4];
    const int* sparse_i   = (const int*)d_in[5];
    const int* sparse_j   = (const int*)d_in[6];
    float* ws  = (float*)d_ws;
    float* out = (float*)d_out;

    k_ab <<<128, B, 0, stream>>>(Zp, Gate, sample_idx, A, ws);
    k_x  <<<320, B, 0, stream>>>(beta, sample_idx, ws);
    k_pe <<<GPE, B, 0, stream>>>(beta, sparse_i, sparse_j, ws);
    k_fin<<<1,   B, 0, stream>>>(ws, out);
}